// Round 7
// baseline (171.390 us; speedup 1.0000x reference)
//
#include <hip/hip_runtime.h>
#include <math.h>

#define NBATCH 2048

typedef unsigned short ushortT;
typedef __attribute__((ext_vector_type(8))) short bf16x8;
typedef __attribute__((ext_vector_type(4))) float f32x4;

__device__ __forceinline__ ushortT f2bf(float f) {
  union { float f; unsigned u; } v; v.f = f;
  unsigned r = v.u + 0x7FFF + ((v.u >> 16) & 1);
  return (ushortT)(r >> 16);
}
__device__ __forceinline__ float bf2f(ushortT h) {
  union { float f; unsigned u; } v; v.u = ((unsigned)h) << 16; return v.f;
}

// ws ushort layout:
//   w2t_hi [0,18432)  w2t_lo [18432,36864)           [tap][co][ci]
//   w3t_hi [36864,73728) w3t_lo [73728,110592)       [tap][co][ci]
//   wd1f_hi [110592,311296) wd1f_lo [311296,512000)  B-frag-major [nt][kk][lane][8]
//   s3 flatten [512000,+6422528)                     [img][3136] (NHWC flatten,
//     bf16; per-block CONTIGUOUS 6272B store -> full-line single-writer writes)
//   w1t_hi [6934528,+1024) w1t_lo [6935552,+1024)    [n][k32] (9 taps + 23 zero)
//   hv f32 [byte 13873152, +512KB)                   [img][64] relu'd dense1 out
#define WD1F_HI 110592
#define WD1F_LO 311296
#define S3F_OFF 512000
#define W1T_HI  6934528
#define W1T_LO  6935552
#define HVF_OFF 3468288   // float index into (float*)d_ws

// grid 266: blk 0..48 wd1 frag-major tiles; 49..120 w2t; 121..264 w3t; 265 w1t
__global__ __launch_bounds__(256) void prep_w(const float* __restrict__ w1,
                                              const float* __restrict__ w2,
                                              const float* __restrict__ w3,
                                              const float* __restrict__ wd1,
                                              ushortT* __restrict__ ws) {
  __shared__ float tile[64][65];
  const int blk = blockIdx.x, t = threadIdx.x;
  if (blk < 49) {
    const int ci0 = blk * 64;               // covers kk0 = blk*2, blk*2+1
    #pragma unroll
    for (int i = 0; i < 16; ++i) {
      int idx = i * 256 + t;
      int ci_l = idx >> 6, co = idx & 63;
      tile[ci_l][co] = wd1[(ci0 + ci_l) * 64 + co];
    }
    __syncthreads();
    const int lane = t & 63, kkl = (t >> 6) & 1, nth = t >> 7;
    const int ln15 = lane & 15, quad = lane >> 4;
    const int kk = blk * 2 + kkl;
    #pragma unroll
    for (int ni = 0; ni < 2; ++ni) {
      int nt = nth * 2 + ni;
      union { ushortT s[8]; bf16x8 v; } uh, ul;
      #pragma unroll
      for (int j = 0; j < 8; ++j) {
        float w = tile[kkl * 32 + quad * 8 + j][nt * 16 + ln15];
        ushortT hb = f2bf(w);
        uh.s[j] = hb;
        ul.s[j] = f2bf(w - bf2f(hb));
      }
      long o = ((long)(nt * 98 + kk) * 64 + lane) * 8;
      *(bf16x8*)(ws + WD1F_HI + o) = uh.v;
      *(bf16x8*)(ws + WD1F_LO + o) = ul.v;
    }
  } else if (blk < 121) {
    int i = (blk - 49) * 256 + t;                 // [0,18432)
    int tap = i / 2048, r = i - tap * 2048, ci = r >> 6, co = r & 63;
    float w = w2[i];
    ushortT hb = f2bf(w);
    ushortT lb = f2bf(w - bf2f(hb));
    int o = (tap * 64 + co) * 32 + ci;
    ws[o] = hb; ws[18432 + o] = lb;
  } else if (blk < 265) {
    int j = (blk - 121) * 256 + t;                // [0,36864)
    int tap = j >> 12, r = j & 4095, ci = r >> 6, co = r & 63;
    float w = w3[j];
    ushortT hb = f2bf(w);
    ushortT lb = f2bf(w - bf2f(hb));
    int o = (tap * 64 + co) * 64 + ci;
    ws[36864 + o] = hb; ws[73728 + o] = lb;
  } else {
    if (t < 32) {
      int n = t;
      #pragma unroll
      for (int k = 0; k < 32; ++k) {
        float w = (k < 9) ? w1[k * 32 + n] : 0.f;
        ushortT hb = f2bf(w);
        ws[W1T_HI + n * 32 + k] = hb;
        ws[W1T_LO + n * 32 + k] = f2bf(w - bf2f(hb));
      }
    }
  }
}

// ---- fully-MFMA conv pipeline: conv1+pool, conv2+pool, conv3 -> s3 flatten bf16
// R6 base + (a) stage-1 unroll 2 (overlap independent T iterations),
// (b) stage-2 cur/nxt B prefetch (hide per-tap L2 latency),
// (c) stage-3 s2u kc-swap swizzle: logical chunk (quad,kc) of row r stored at
//     kc ^ ((r>>3)&1) — breaks the dr=8 bank collision of the 144B row stride
//     (36 dw = 4 mod 32) at 2 VALU/read; write side is ch ^ 32 on r&8 rows.
__global__ __launch_bounds__(256, 5) void conv_fused(
    const float* __restrict__ xg, const float* __restrict__ b1g,
    const float* __restrict__ b2g, const float* __restrict__ b3g,
    const ushortT* __restrict__ wsu, ushortT* __restrict__ s3g)
{
  __shared__ __align__(16) unsigned char smem[32144];
  ushortT* s1u  = (ushortT*)smem;
  ushortT* s2u  = (ushortT*)(smem + 20480);       // stage 2+
  ushortT* s3l  = (ushortT*)smem;                 // [49][72] after stage2 (s1u dead)
  ushortT* xinb = (ushortT*)(smem + 20480);       // stage 1 only

  const int t = threadIdx.x, b = blockIdx.x;
  const int lane = t & 63, wid = t >> 6;
  const int ln15 = lane & 15, quad = lane >> 4;

  // phase 0: zero s1u + xinb
  {
    uint4 z = make_uint4(0u, 0u, 0u, 0u);
    uint4* p = (uint4*)s1u;
    for (int i = t; i < 1280; i += 256) p[i] = z;
    unsigned* px = (unsigned*)xinb;
    for (int i = t; i < 465; i += 256) px[i] = 0u;
  }
  __syncthreads();
  // phase 1: load image as bf16
  const float* xb = xg + (long)b * 784;
  for (int i = t; i < 784; i += 256) {
    int y = i / 28, x = i - y * 28;
    xinb[(y + 1) * 31 + (x + 1)] = f2bf(xb[i]);
  }
  __syncthreads();

  // ---- stage 1: conv1 (1->32) MFMA, per-lane direct A-fragment from xinb.
  {
    const float bia0 = b1g[ln15];
    const float bia1 = b1g[16 + ln15];
    bf16x8 bh0 = *(const bf16x8*)(wsu + W1T_HI + ln15 * 32 + quad * 8);
    bf16x8 bl0 = *(const bf16x8*)(wsu + W1T_LO + ln15 * 32 + quad * 8);
    bf16x8 bh1 = *(const bf16x8*)(wsu + W1T_HI + (16 + ln15) * 32 + quad * 8);
    bf16x8 bl1 = *(const bf16x8*)(wsu + W1T_LO + (16 + ln15) * 32 + quad * 8);
    #pragma unroll 2
    for (int T = wid; T < 49; T += 4) {
      int pr = T * 4 + (ln15 >> 2);           // this lane's conv-row pool pixel
      int q  = ln15 & 3;                      // quadrant within pool pixel
      int py = pr / 14, px = pr - py * 14;
      const ushortT* xr = xinb + (2 * py + (q >> 1)) * 31 + 2 * px + (q & 1);
      union { unsigned d[4]; bf16x8 v; } ua;
      ua.d[0] = 0u; ua.d[1] = 0u; ua.d[2] = 0u; ua.d[3] = 0u;
      if (quad == 0) {
        ua.d[0] = xr[0]  | ((unsigned)xr[1]  << 16);
        ua.d[1] = xr[2]  | ((unsigned)xr[31] << 16);
        ua.d[2] = xr[32] | ((unsigned)xr[33] << 16);
        ua.d[3] = xr[62] | ((unsigned)xr[63] << 16);
      } else if (quad == 1) {
        ua.d[0] = xr[64];
      }
      f32x4 a0 = (f32x4){bia0, bia0, bia0, bia0};
      f32x4 a1 = (f32x4){bia1, bia1, bia1, bia1};
      a0 = __builtin_amdgcn_mfma_f32_16x16x32_bf16(ua.v, bh0, a0, 0, 0, 0);
      a0 = __builtin_amdgcn_mfma_f32_16x16x32_bf16(ua.v, bl0, a0, 0, 0, 0);
      a1 = __builtin_amdgcn_mfma_f32_16x16x32_bf16(ua.v, bh1, a1, 0, 0, 0);
      a1 = __builtin_amdgcn_mfma_f32_16x16x32_bf16(ua.v, bl1, a1, 0, 0, 0);
      int po = T * 4 + quad;
      int oy = po / 14, ox = po - oy * 14;
      int row = (oy + 1) * 16 + ox + 1;
      float m0 = fmaxf(fmaxf(a0[0], a0[1]), fmaxf(a0[2], a0[3]));
      float m1 = fmaxf(fmaxf(a1[0], a1[1]), fmaxf(a1[2], a1[3]));
      s1u[row * 40 + ln15]      = f2bf(fmaxf(m0, 0.f));
      s1u[row * 40 + 16 + ln15] = f2bf(fmaxf(m1, 0.f));
    }
  }
  __syncthreads();
  // zero s2u region (xinb dead); all-zero rows are swizzle-invariant
  {
    uint4 z = make_uint4(0u, 0u, 0u, 0u);
    uint4* p = (uint4*)s2u;                        // 5832 ushorts = 729 uint4
    for (int i = t; i < 729; i += 256) p[i] = z;
  }
  __syncthreads();

  // ---- stage 2: conv2 (32->64) MFMA, pool-morton M; cur/nxt B prefetch;
  // pool+relu -> s2u (kc-swap swizzled write)
  {
    const int nth = wid >> 1, mtg = wid & 1;
    const int nmt = mtg ? 6 : 7;
    const int nt0 = nth * 2;
    int abase[7];
    #pragma unroll
    for (int k = 0; k < 7; ++k) {
      int mt = mtg + 2 * k;
      int m = mt * 16 + ln15;
      int pp = m >> 2; if (pp > 48) pp = 48;
      int qq = m & 3;
      int py = pp / 7, px = pp - py * 7;
      int oy = 2 * py + (qq >> 1), ox = 2 * px + (qq & 1);
      abase[k] = (oy * 16 + ox) * 80 + quad * 16;
    }
    const float bia0 = b2g[nt0 * 16 + ln15];
    const float bia1 = b2g[(nt0 + 1) * 16 + ln15];
    f32x4 acc[7][2];
    #pragma unroll
    for (int k = 0; k < 7; ++k) {
      acc[k][0] = (f32x4){bia0, bia0, bia0, bia0};
      acc[k][1] = (f32x4){bia1, bia1, bia1, bia1};
    }
    const char* s1b = (const char*)s1u;
    const ushortT* wbase = wsu + (nt0 * 16 + ln15) * 32 + quad * 8;
    bf16x8 cur[4], nxt[4];
    {
      const ushortT* bp = wbase;
      cur[0] = *(const bf16x8*)bp;
      cur[1] = *(const bf16x8*)(bp + 18432);
      cur[2] = *(const bf16x8*)(bp + 512);
      cur[3] = *(const bf16x8*)(bp + 18432 + 512);
    }
    #pragma unroll 1
    for (int tap = 0; tap < 9; ++tap) {
      {
        int tn = tap < 8 ? tap + 1 : 8;
        const ushortT* bp = wbase + tn * 2048;
        nxt[0] = *(const bf16x8*)bp;
        nxt[1] = *(const bf16x8*)(bp + 18432);
        nxt[2] = *(const bf16x8*)(bp + 512);
        nxt[3] = *(const bf16x8*)(bp + 18432 + 512);
      }
      int ky = tap / 3, kx = tap - (tap / 3) * 3;
      int soff = (ky * 16 + kx) * 80;
      #pragma unroll
      for (int k = 0; k < 7; ++k) {
        if (k < nmt) {
          bf16x8 a = *(const bf16x8*)(s1b + abase[k] + soff);
          acc[k][0] = __builtin_amdgcn_mfma_f32_16x16x32_bf16(a, cur[0], acc[k][0], 0, 0, 0);
          acc[k][0] = __builtin_amdgcn_mfma_f32_16x16x32_bf16(a, cur[1], acc[k][0], 0, 0, 0);
          acc[k][1] = __builtin_amdgcn_mfma_f32_16x16x32_bf16(a, cur[2], acc[k][1], 0, 0, 0);
          acc[k][1] = __builtin_amdgcn_mfma_f32_16x16x32_bf16(a, cur[3], acc[k][1], 0, 0, 0);
        }
      }
      #pragma unroll
      for (int i = 0; i < 4; ++i) cur[i] = nxt[i];
    }
    #pragma unroll
    for (int k = 0; k < 7; ++k) {
      if (k < nmt) {
        int mt = mtg + 2 * k;
        int pp = mt * 4 + quad;
        if (pp < 49) {
          int py = pp / 7, px = pp - py * 7;
          int grow = (py + 1) * 9 + px + 1;
          int swz = (grow & 8) << 2;           // 0 or 32 ushorts (64B)
          f32x4 v0 = acc[k][0], v1 = acc[k][1];
          float p0 = fmaxf(fmaxf(v0.x, v0.y), fmaxf(v0.z, v0.w));
          float p1 = fmaxf(fmaxf(v1.x, v1.y), fmaxf(v1.z, v1.w));
          s2u[grow * 72 + ((nt0 * 16 + ln15) ^ swz)]       = f2bf(fmaxf(p0, 0.f));
          s2u[grow * 72 + (((nt0 + 1) * 16 + ln15) ^ swz)] = f2bf(fmaxf(p1, 0.f));
        }
      }
    }
  }
  __syncthreads();

  // ---- stage 3: conv3 (64->64) MFMA + relu -> s3l LDS, then contiguous global
  // A-reads from s2u use the kc-swap swizzle: chunk kc of row rr is at kc^((rr>>3)&1)
  {
    int rowb2[4];
    #pragma unroll
    for (int mt = 0; mt < 4; ++mt) {
      int op = mt * 16 + ln15; if (op > 48) op = 48;
      int oy = op / 7, ox = op - (op / 7) * 7;
      rowb2[mt] = oy * 9 + ox;
    }
    const float bia = b3g[wid * 16 + ln15];
    f32x4 acc3[4];
    #pragma unroll
    for (int mt = 0; mt < 4; ++mt) acc3[mt] = (f32x4){bia, bia, bia, bia};
    const char* s2b = (const char*)s2u;
    const ushortT* w3base = wsu + 36864 + (wid * 16 + ln15) * 64 + quad * 8;
    bf16x8 cur[4], nxt[4];
    {
      const ushortT* bp = w3base;
      cur[0] = *(const bf16x8*)bp;
      cur[1] = *(const bf16x8*)(bp + 36864);
      cur[2] = *(const bf16x8*)(bp + 32);
      cur[3] = *(const bf16x8*)(bp + 36864 + 32);
    }
    #pragma unroll 1
    for (int tap = 0; tap < 9; ++tap) {
      {
        int tn = tap < 8 ? tap + 1 : 8;
        const ushortT* bp = w3base + tn * 4096;
        nxt[0] = *(const bf16x8*)bp;
        nxt[1] = *(const bf16x8*)(bp + 36864);
        nxt[2] = *(const bf16x8*)(bp + 32);
        nxt[3] = *(const bf16x8*)(bp + 36864 + 32);
      }
      int ky = tap / 3, kx = tap - (tap / 3) * 3;
      int trow = ky * 9 + kx;
      #pragma unroll
      for (int kc = 0; kc < 2; ++kc) {
        #pragma unroll
        for (int mt = 0; mt < 4; ++mt) {
          int rr = rowb2[mt] + trow;
          int kcs = (kc ^ ((rr >> 3) & 1)) << 6;
          bf16x8 a = *(const bf16x8*)(s2b + rr * 144 + quad * 16 + kcs);
          acc3[mt] = __builtin_amdgcn_mfma_f32_16x16x32_bf16(a, cur[kc * 2],     acc3[mt], 0, 0, 0);
          acc3[mt] = __builtin_amdgcn_mfma_f32_16x16x32_bf16(a, cur[kc * 2 + 1], acc3[mt], 0, 0, 0);
        }
      }
      #pragma unroll
      for (int i = 0; i < 4; ++i) cur[i] = nxt[i];
    }
    // write to s3l [op][72] (s1u region dead; stage-2 reads done via barrier above)
    #pragma unroll
    for (int mt = 0; mt < 4; ++mt)
      #pragma unroll
      for (int r = 0; r < 4; ++r) {
        int op = mt * 16 + quad * 4 + r;
        if (op < 49) s3l[op * 72 + wid * 16 + ln15] = f2bf(fmaxf(acc3[mt][r], 0.f));
      }
  }
  __syncthreads();
  // cooperative CONTIGUOUS store: s3[img][3136], chunk i -> offset i*8 ushorts.
  {
    ushortT* dst = s3g + (long)b * 3136;
    for (int i = t; i < 392; i += 256) {
      uint4 v = *(const uint4*)(s3l + (i >> 3) * 72 + (i & 7) * 8);
      *(uint4*)(dst + i * 8) = v;
    }
  }
}

// ---- dense1 half-block: 256 blocks (g = bid>>1, nh = bid&1), 16 waves =
// 2 n-tiles x 8 K-ranges (12-13 kk each). A read per-lane from flatten s3.
__global__ __launch_bounds__(1024) void dense1_half(
    const ushortT* __restrict__ ws, const float* __restrict__ bd1g,
    float* __restrict__ hvg)
{
  __shared__ float part[16 * 256];   // [(kq*2+nt2)][im*16+c15]
  const int t = threadIdx.x;
  const int lane = t & 63, wid = t >> 6;
  const int ln15 = lane & 15, quad = lane >> 4;
  const int nt2 = wid & 1, kq = wid >> 1;
  const int bid = blockIdx.x;
  const int g = bid >> 1, nh = bid & 1;
  const int nt = nh * 2 + nt2;
  const int ks = kq * 12 + (kq < 2 ? kq : 2);   // 13,13,12,12,12,12,12,12
  const int n  = (kq < 2) ? 13 : 12;

  const ushortT* a_p = ws + S3F_OFF + (long)(g * 16 + ln15) * 3136
                        + (long)ks * 32 + quad * 8;
  const ushortT* h_p = ws + WD1F_HI + ((long)(nt * 98 + ks)) * 512 + lane * 8;
  const ushortT* l_p = ws + WD1F_LO + ((long)(nt * 98 + ks)) * 512 + lane * 8;

  bf16x8 a  = *(const bf16x8*)a_p;
  bf16x8 wh = *(const bf16x8*)h_p;
  bf16x8 wl = *(const bf16x8*)l_p;
  f32x4 ac0 = (f32x4){0.f, 0.f, 0.f, 0.f};
  f32x4 ac1 = (f32x4){0.f, 0.f, 0.f, 0.f};
  #pragma unroll 2
  for (int i = 1; i < n; ++i) {
    bf16x8 na = *(const bf16x8*)(a_p + i * 32);
    bf16x8 nh2 = *(const bf16x8*)(h_p + i * 512);
    bf16x8 nl2 = *(const bf16x8*)(l_p + i * 512);
    ac0 = __builtin_amdgcn_mfma_f32_16x16x32_bf16(a, wh, ac0, 0, 0, 0);
    ac1 = __builtin_amdgcn_mfma_f32_16x16x32_bf16(a, wl, ac1, 0, 0, 0);
    a = na; wh = nh2; wl = nl2;
  }
  ac0 = __builtin_amdgcn_mfma_f32_16x16x32_bf16(a, wh, ac0, 0, 0, 0);
  ac1 = __builtin_amdgcn_mfma_f32_16x16x32_bf16(a, wl, ac1, 0, 0, 0);
  float* dst = part + (kq * 2 + nt2) * 256;
  #pragma unroll
  for (int r = 0; r < 4; ++r)
    dst[(quad * 4 + r) * 16 + ln15] = ac0[r] + ac1[r];
  __syncthreads();

  if (t < 512) {
    const int im = t >> 5, ch = t & 31;
    const int ntc = ch >> 4, c15 = ch & 15;
    float v = bd1g[nh * 32 + ch];
    #pragma unroll
    for (int k8 = 0; k8 < 8; ++k8)
      v += part[(k8 * 2 + ntc) * 256 + im * 16 + c15];
    hvg[(long)(g * 16 + im) * 64 + nh * 32 + ch] = fmaxf(v, 0.f);
  }
}

// ---- dense2 + softmax: 512 blocks x 256 thr, 4 images each
__global__ __launch_bounds__(256) void dense_fin(
    const float* __restrict__ hvg, const float* __restrict__ wd2g,
    const float* __restrict__ bd2g, float* __restrict__ out)
{
  __shared__ float shv[4][64];
  __shared__ float lg[4][12];
  __shared__ float le[4][12];
  const int t = threadIdx.x;
  const int il = t >> 6, ch = t & 63;
  const long img = (long)blockIdx.x * 4 + il;
  shv[il][ch] = hvg[img * 64 + ch];
  __syncthreads();
  if (ch < 10) {
    float a2 = bd2g[ch];
    #pragma unroll
    for (int k = 0; k < 64; ++k) a2 = fmaf(shv[il][k], wd2g[k * 10 + ch], a2);
    lg[il][ch] = a2;
  }
  __syncthreads();
  if (ch < 10) {
    float m = lg[il][0];
    #pragma unroll
    for (int i = 1; i < 10; ++i) m = fmaxf(m, lg[il][i]);
    le[il][ch] = expf(lg[il][ch] - m);
  }
  __syncthreads();
  if (ch < 10) {
    float s = 0.f;
    #pragma unroll
    for (int i = 0; i < 10; ++i) s += le[il][i];
    out[img * 10 + ch] = le[il][ch] / s;
  }
}

extern "C" void kernel_launch(void* const* d_in, const int* in_sizes, int n_in,
                              void* d_out, int out_size, void* d_ws, size_t ws_size,
                              hipStream_t stream) {
  (void)in_sizes; (void)n_in; (void)out_size; (void)ws_size;
  const float* x   = (const float*)d_in[0];
  const float* w1  = (const float*)d_in[1];
  const float* b1  = (const float*)d_in[2];
  const float* w2  = (const float*)d_in[3];
  const float* b2  = (const float*)d_in[4];
  const float* w3  = (const float*)d_in[5];
  const float* b3  = (const float*)d_in[6];
  const float* wd1 = (const float*)d_in[7];
  const float* bd1 = (const float*)d_in[8];
  const float* wd2 = (const float*)d_in[9];
  const float* bd2 = (const float*)d_in[10];
  float* out = (float*)d_out;
  ushortT* wsu = (ushortT*)d_ws;
  ushortT* s3g = wsu + S3F_OFF;
  float* hvg = (float*)d_ws + HVF_OFF;

  hipLaunchKernelGGL(prep_w, dim3(266), dim3(256), 0, stream, w1, w2, w3, wd1, wsu);
  hipLaunchKernelGGL(conv_fused, dim3(NBATCH), dim3(256), 0, stream,
                     x, b1, b2, b3, wsu, s3g);
  hipLaunchKernelGGL(dense1_half, dim3(256), dim3(1024), 0, stream,
                     wsu, bd1, hvg);
  hipLaunchKernelGGL(dense_fin, dim3(NBATCH / 4), dim3(256), 0, stream,
                     hvg, wd2, bd2, out);
}

// Round 8
// 152.910 us; speedup vs baseline: 1.1209x; 1.1209x over previous
//
#include <hip/hip_runtime.h>
#include <math.h>

#define NBATCH 2048

typedef unsigned short ushortT;
typedef __attribute__((ext_vector_type(8))) short bf16x8;
typedef __attribute__((ext_vector_type(4))) float f32x4;

__device__ __forceinline__ ushortT f2bf(float f) {
  union { float f; unsigned u; } v; v.f = f;
  unsigned r = v.u + 0x7FFF + ((v.u >> 16) & 1);
  return (ushortT)(r >> 16);
}
__device__ __forceinline__ float bf2f(ushortT h) {
  union { float f; unsigned u; } v; v.u = ((unsigned)h) << 16; return v.f;
}

// ws ushort layout:
//   w2t_hi [0,18432)  w2t_lo [18432,36864)           [tap][co][ci]
//   w3t_hi [36864,73728) w3t_lo [73728,110592)       [tap][co][ci]
//   wd1f_hi [110592,311296) wd1f_lo [311296,512000)  B-frag-major [nt][kk][lane][8]
//   s3 flatten [512000,+6422528)                     [img][3136] (NHWC flatten,
//     bf16; per-block CONTIGUOUS 6272B store -> full-line single-writer writes)
//   w1t_hi [6934528,+1024) w1t_lo [6935552,+1024)    [n][k32] (9 taps + 23 zero)
//   hv f32 [byte 13873152, +512KB)                   [img][64] relu'd dense1 out
#define WD1F_HI 110592
#define WD1F_LO 311296
#define S3F_OFF 512000
#define W1T_HI  6934528
#define W1T_LO  6935552
#define HVF_OFF 3468288   // float index into (float*)d_ws

// grid 266: blk 0..48 wd1 frag-major tiles; 49..120 w2t; 121..264 w3t; 265 w1t
__global__ __launch_bounds__(256) void prep_w(const float* __restrict__ w1,
                                              const float* __restrict__ w2,
                                              const float* __restrict__ w3,
                                              const float* __restrict__ wd1,
                                              ushortT* __restrict__ ws) {
  __shared__ float tile[64][65];
  const int blk = blockIdx.x, t = threadIdx.x;
  if (blk < 49) {
    const int ci0 = blk * 64;               // covers kk0 = blk*2, blk*2+1
    #pragma unroll
    for (int i = 0; i < 16; ++i) {
      int idx = i * 256 + t;
      int ci_l = idx >> 6, co = idx & 63;
      tile[ci_l][co] = wd1[(ci0 + ci_l) * 64 + co];
    }
    __syncthreads();
    const int lane = t & 63, kkl = (t >> 6) & 1, nth = t >> 7;
    const int ln15 = lane & 15, quad = lane >> 4;
    const int kk = blk * 2 + kkl;
    #pragma unroll
    for (int ni = 0; ni < 2; ++ni) {
      int nt = nth * 2 + ni;
      union { ushortT s[8]; bf16x8 v; } uh, ul;
      #pragma unroll
      for (int j = 0; j < 8; ++j) {
        float w = tile[kkl * 32 + quad * 8 + j][nt * 16 + ln15];
        ushortT hb = f2bf(w);
        uh.s[j] = hb;
        ul.s[j] = f2bf(w - bf2f(hb));
      }
      long o = ((long)(nt * 98 + kk) * 64 + lane) * 8;
      *(bf16x8*)(ws + WD1F_HI + o) = uh.v;
      *(bf16x8*)(ws + WD1F_LO + o) = ul.v;
    }
  } else if (blk < 121) {
    int i = (blk - 49) * 256 + t;                 // [0,18432)
    int tap = i / 2048, r = i - tap * 2048, ci = r >> 6, co = r & 63;
    float w = w2[i];
    ushortT hb = f2bf(w);
    ushortT lb = f2bf(w - bf2f(hb));
    int o = (tap * 64 + co) * 32 + ci;
    ws[o] = hb; ws[18432 + o] = lb;
  } else if (blk < 265) {
    int j = (blk - 121) * 256 + t;                // [0,36864)
    int tap = j >> 12, r = j & 4095, ci = r >> 6, co = r & 63;
    float w = w3[j];
    ushortT hb = f2bf(w);
    ushortT lb = f2bf(w - bf2f(hb));
    int o = (tap * 64 + co) * 64 + ci;
    ws[36864 + o] = hb; ws[73728 + o] = lb;
  } else {
    if (t < 32) {
      int n = t;
      #pragma unroll
      for (int k = 0; k < 32; ++k) {
        float w = (k < 9) ? w1[k * 32 + n] : 0.f;
        ushortT hb = f2bf(w);
        ws[W1T_HI + n * 32 + k] = hb;
        ws[W1T_LO + n * 32 + k] = f2bf(w - bf2f(hb));
      }
    }
  }
}

// ---- fully-MFMA conv pipeline: conv1+pool, conv2+pool, conv3 -> s3 flatten bf16
// launch_bounds (256,4): the previous (256,5) cap (~102 unified VGPR+AGPR/wave)
// forced scratch spills once stage-2 held acc[7][2] + cur/nxt prefetch
// (R5/R7 signature: WRITE_SIZE 12.5->51-60MB partial-line scratch RMW, +19us).
// Occupancy was measured pinned at ~12 waves/CU under both bounds, so the
// relaxation costs nothing and removes the spill pressure.
__global__ __launch_bounds__(256, 4) void conv_fused(
    const float* __restrict__ xg, const float* __restrict__ b1g,
    const float* __restrict__ b2g, const float* __restrict__ b3g,
    const ushortT* __restrict__ wsu, ushortT* __restrict__ s3g)
{
  __shared__ __align__(16) unsigned char smem[32144];
  ushortT* s1u  = (ushortT*)smem;
  ushortT* s2u  = (ushortT*)(smem + 20480);       // stage 2+
  ushortT* s3l  = (ushortT*)smem;                 // [49][72] after stage2 (s1u dead)
  ushortT* xinb = (ushortT*)(smem + 20480);       // stage 1 only

  const int t = threadIdx.x, b = blockIdx.x;
  const int lane = t & 63, wid = t >> 6;
  const int ln15 = lane & 15, quad = lane >> 4;

  // phase 0: zero s1u + xinb
  {
    uint4 z = make_uint4(0u, 0u, 0u, 0u);
    uint4* p = (uint4*)s1u;
    for (int i = t; i < 1280; i += 256) p[i] = z;
    unsigned* px = (unsigned*)xinb;
    for (int i = t; i < 465; i += 256) px[i] = 0u;
  }
  __syncthreads();
  // phase 1: load image as bf16
  const float* xb = xg + (long)b * 784;
  for (int i = t; i < 784; i += 256) {
    int y = i / 28, x = i - y * 28;
    xinb[(y + 1) * 31 + (x + 1)] = f2bf(xb[i]);
  }
  __syncthreads();

  // ---- stage 1: conv1 (1->32) MFMA, per-lane direct A-fragment from xinb.
  {
    const float bia0 = b1g[ln15];
    const float bia1 = b1g[16 + ln15];
    bf16x8 bh0 = *(const bf16x8*)(wsu + W1T_HI + ln15 * 32 + quad * 8);
    bf16x8 bl0 = *(const bf16x8*)(wsu + W1T_LO + ln15 * 32 + quad * 8);
    bf16x8 bh1 = *(const bf16x8*)(wsu + W1T_HI + (16 + ln15) * 32 + quad * 8);
    bf16x8 bl1 = *(const bf16x8*)(wsu + W1T_LO + (16 + ln15) * 32 + quad * 8);
    #pragma unroll 2
    for (int T = wid; T < 49; T += 4) {
      int pr = T * 4 + (ln15 >> 2);           // this lane's conv-row pool pixel
      int q  = ln15 & 3;                      // quadrant within pool pixel
      int py = pr / 14, px = pr - py * 14;
      const ushortT* xr = xinb + (2 * py + (q >> 1)) * 31 + 2 * px + (q & 1);
      union { unsigned d[4]; bf16x8 v; } ua;
      ua.d[0] = 0u; ua.d[1] = 0u; ua.d[2] = 0u; ua.d[3] = 0u;
      if (quad == 0) {
        ua.d[0] = xr[0]  | ((unsigned)xr[1]  << 16);
        ua.d[1] = xr[2]  | ((unsigned)xr[31] << 16);
        ua.d[2] = xr[32] | ((unsigned)xr[33] << 16);
        ua.d[3] = xr[62] | ((unsigned)xr[63] << 16);
      } else if (quad == 1) {
        ua.d[0] = xr[64];
      }
      f32x4 a0 = (f32x4){bia0, bia0, bia0, bia0};
      f32x4 a1 = (f32x4){bia1, bia1, bia1, bia1};
      a0 = __builtin_amdgcn_mfma_f32_16x16x32_bf16(ua.v, bh0, a0, 0, 0, 0);
      a0 = __builtin_amdgcn_mfma_f32_16x16x32_bf16(ua.v, bl0, a0, 0, 0, 0);
      a1 = __builtin_amdgcn_mfma_f32_16x16x32_bf16(ua.v, bh1, a1, 0, 0, 0);
      a1 = __builtin_amdgcn_mfma_f32_16x16x32_bf16(ua.v, bl1, a1, 0, 0, 0);
      int po = T * 4 + quad;
      int oy = po / 14, ox = po - oy * 14;
      int row = (oy + 1) * 16 + ox + 1;
      float m0 = fmaxf(fmaxf(a0[0], a0[1]), fmaxf(a0[2], a0[3]));
      float m1 = fmaxf(fmaxf(a1[0], a1[1]), fmaxf(a1[2], a1[3]));
      s1u[row * 40 + ln15]      = f2bf(fmaxf(m0, 0.f));
      s1u[row * 40 + 16 + ln15] = f2bf(fmaxf(m1, 0.f));
    }
  }
  __syncthreads();
  // zero s2u region (xinb dead); all-zero rows are swizzle-invariant
  {
    uint4 z = make_uint4(0u, 0u, 0u, 0u);
    uint4* p = (uint4*)s2u;                        // 5832 ushorts = 729 uint4
    for (int i = t; i < 729; i += 256) p[i] = z;
  }
  __syncthreads();

  // ---- stage 2: conv2 (32->64) MFMA, pool-morton M; cur/nxt B prefetch;
  // pool+relu -> s2u (kc-swap swizzled write)
  {
    const int nth = wid >> 1, mtg = wid & 1;
    const int nmt = mtg ? 6 : 7;
    const int nt0 = nth * 2;
    int abase[7];
    #pragma unroll
    for (int k = 0; k < 7; ++k) {
      int mt = mtg + 2 * k;
      int m = mt * 16 + ln15;
      int pp = m >> 2; if (pp > 48) pp = 48;
      int qq = m & 3;
      int py = pp / 7, px = pp - py * 7;
      int oy = 2 * py + (qq >> 1), ox = 2 * px + (qq & 1);
      abase[k] = (oy * 16 + ox) * 80 + quad * 16;
    }
    const float bia0 = b2g[nt0 * 16 + ln15];
    const float bia1 = b2g[(nt0 + 1) * 16 + ln15];
    f32x4 acc[7][2];
    #pragma unroll
    for (int k = 0; k < 7; ++k) {
      acc[k][0] = (f32x4){bia0, bia0, bia0, bia0};
      acc[k][1] = (f32x4){bia1, bia1, bia1, bia1};
    }
    const char* s1b = (const char*)s1u;
    const ushortT* wbase = wsu + (nt0 * 16 + ln15) * 32 + quad * 8;
    bf16x8 cur[4], nxt[4];
    {
      const ushortT* bp = wbase;
      cur[0] = *(const bf16x8*)bp;
      cur[1] = *(const bf16x8*)(bp + 18432);
      cur[2] = *(const bf16x8*)(bp + 512);
      cur[3] = *(const bf16x8*)(bp + 18432 + 512);
    }
    #pragma unroll 1
    for (int tap = 0; tap < 9; ++tap) {
      {
        int tn = tap < 8 ? tap + 1 : 8;
        const ushortT* bp = wbase + tn * 2048;
        nxt[0] = *(const bf16x8*)bp;
        nxt[1] = *(const bf16x8*)(bp + 18432);
        nxt[2] = *(const bf16x8*)(bp + 512);
        nxt[3] = *(const bf16x8*)(bp + 18432 + 512);
      }
      int ky = tap / 3, kx = tap - (tap / 3) * 3;
      int soff = (ky * 16 + kx) * 80;
      #pragma unroll
      for (int k = 0; k < 7; ++k) {
        if (k < nmt) {
          bf16x8 a = *(const bf16x8*)(s1b + abase[k] + soff);
          acc[k][0] = __builtin_amdgcn_mfma_f32_16x16x32_bf16(a, cur[0], acc[k][0], 0, 0, 0);
          acc[k][0] = __builtin_amdgcn_mfma_f32_16x16x32_bf16(a, cur[1], acc[k][0], 0, 0, 0);
          acc[k][1] = __builtin_amdgcn_mfma_f32_16x16x32_bf16(a, cur[2], acc[k][1], 0, 0, 0);
          acc[k][1] = __builtin_amdgcn_mfma_f32_16x16x32_bf16(a, cur[3], acc[k][1], 0, 0, 0);
        }
      }
      #pragma unroll
      for (int i = 0; i < 4; ++i) cur[i] = nxt[i];
    }
    #pragma unroll
    for (int k = 0; k < 7; ++k) {
      if (k < nmt) {
        int mt = mtg + 2 * k;
        int pp = mt * 4 + quad;
        if (pp < 49) {
          int py = pp / 7, px = pp - py * 7;
          int grow = (py + 1) * 9 + px + 1;
          int swz = (grow & 8) << 2;           // 0 or 32 ushorts (64B)
          f32x4 v0 = acc[k][0], v1 = acc[k][1];
          float p0 = fmaxf(fmaxf(v0.x, v0.y), fmaxf(v0.z, v0.w));
          float p1 = fmaxf(fmaxf(v1.x, v1.y), fmaxf(v1.z, v1.w));
          s2u[grow * 72 + ((nt0 * 16 + ln15) ^ swz)]       = f2bf(fmaxf(p0, 0.f));
          s2u[grow * 72 + (((nt0 + 1) * 16 + ln15) ^ swz)] = f2bf(fmaxf(p1, 0.f));
        }
      }
    }
  }
  __syncthreads();

  // ---- stage 3: conv3 (64->64) MFMA + relu -> s3l LDS, then contiguous global
  // A-reads from s2u use the kc-swap swizzle: chunk kc of row rr is at kc^((rr>>3)&1)
  {
    int rowb2[4];
    #pragma unroll
    for (int mt = 0; mt < 4; ++mt) {
      int op = mt * 16 + ln15; if (op > 48) op = 48;
      int oy = op / 7, ox = op - (op / 7) * 7;
      rowb2[mt] = oy * 9 + ox;
    }
    const float bia = b3g[wid * 16 + ln15];
    f32x4 acc3[4];
    #pragma unroll
    for (int mt = 0; mt < 4; ++mt) acc3[mt] = (f32x4){bia, bia, bia, bia};
    const char* s2b = (const char*)s2u;
    const ushortT* w3base = wsu + 36864 + (wid * 16 + ln15) * 64 + quad * 8;
    bf16x8 cur[4], nxt[4];
    {
      const ushortT* bp = w3base;
      cur[0] = *(const bf16x8*)bp;
      cur[1] = *(const bf16x8*)(bp + 36864);
      cur[2] = *(const bf16x8*)(bp + 32);
      cur[3] = *(const bf16x8*)(bp + 36864 + 32);
    }
    #pragma unroll 1
    for (int tap = 0; tap < 9; ++tap) {
      {
        int tn = tap < 8 ? tap + 1 : 8;
        const ushortT* bp = w3base + tn * 4096;
        nxt[0] = *(const bf16x8*)bp;
        nxt[1] = *(const bf16x8*)(bp + 36864);
        nxt[2] = *(const bf16x8*)(bp + 32);
        nxt[3] = *(const bf16x8*)(bp + 36864 + 32);
      }
      int ky = tap / 3, kx = tap - (tap / 3) * 3;
      int trow = ky * 9 + kx;
      #pragma unroll
      for (int kc = 0; kc < 2; ++kc) {
        #pragma unroll
        for (int mt = 0; mt < 4; ++mt) {
          int rr = rowb2[mt] + trow;
          int kcs = (kc ^ ((rr >> 3) & 1)) << 6;
          bf16x8 a = *(const bf16x8*)(s2b + rr * 144 + quad * 16 + kcs);
          acc3[mt] = __builtin_amdgcn_mfma_f32_16x16x32_bf16(a, cur[kc * 2],     acc3[mt], 0, 0, 0);
          acc3[mt] = __builtin_amdgcn_mfma_f32_16x16x32_bf16(a, cur[kc * 2 + 1], acc3[mt], 0, 0, 0);
        }
      }
      #pragma unroll
      for (int i = 0; i < 4; ++i) cur[i] = nxt[i];
    }
    // write to s3l [op][72] (s1u region dead; stage-2 reads done via barrier above)
    #pragma unroll
    for (int mt = 0; mt < 4; ++mt)
      #pragma unroll
      for (int r = 0; r < 4; ++r) {
        int op = mt * 16 + quad * 4 + r;
        if (op < 49) s3l[op * 72 + wid * 16 + ln15] = f2bf(fmaxf(acc3[mt][r], 0.f));
      }
  }
  __syncthreads();
  // cooperative CONTIGUOUS store: s3[img][3136], chunk i -> offset i*8 ushorts.
  {
    ushortT* dst = s3g + (long)b * 3136;
    for (int i = t; i < 392; i += 256) {
      uint4 v = *(const uint4*)(s3l + (i >> 3) * 72 + (i & 7) * 8);
      *(uint4*)(dst + i * 8) = v;
    }
  }
}

// ---- dense1 half-block: 256 blocks (g = bid>>1, nh = bid&1), 16 waves =
// 2 n-tiles x 8 K-ranges (12-13 kk each). A read per-lane from flatten s3.
__global__ __launch_bounds__(1024) void dense1_half(
    const ushortT* __restrict__ ws, const float* __restrict__ bd1g,
    float* __restrict__ hvg)
{
  __shared__ float part[16 * 256];   // [(kq*2+nt2)][im*16+c15]
  const int t = threadIdx.x;
  const int lane = t & 63, wid = t >> 6;
  const int ln15 = lane & 15, quad = lane >> 4;
  const int nt2 = wid & 1, kq = wid >> 1;
  const int bid = blockIdx.x;
  const int g = bid >> 1, nh = bid & 1;
  const int nt = nh * 2 + nt2;
  const int ks = kq * 12 + (kq < 2 ? kq : 2);   // 13,13,12,12,12,12,12,12
  const int n  = (kq < 2) ? 13 : 12;

  const ushortT* a_p = ws + S3F_OFF + (long)(g * 16 + ln15) * 3136
                        + (long)ks * 32 + quad * 8;
  const ushortT* h_p = ws + WD1F_HI + ((long)(nt * 98 + ks)) * 512 + lane * 8;
  const ushortT* l_p = ws + WD1F_LO + ((long)(nt * 98 + ks)) * 512 + lane * 8;

  bf16x8 a  = *(const bf16x8*)a_p;
  bf16x8 wh = *(const bf16x8*)h_p;
  bf16x8 wl = *(const bf16x8*)l_p;
  f32x4 ac0 = (f32x4){0.f, 0.f, 0.f, 0.f};
  f32x4 ac1 = (f32x4){0.f, 0.f, 0.f, 0.f};
  #pragma unroll 2
  for (int i = 1; i < n; ++i) {
    bf16x8 na = *(const bf16x8*)(a_p + i * 32);
    bf16x8 nh2 = *(const bf16x8*)(h_p + i * 512);
    bf16x8 nl2 = *(const bf16x8*)(l_p + i * 512);
    ac0 = __builtin_amdgcn_mfma_f32_16x16x32_bf16(a, wh, ac0, 0, 0, 0);
    ac1 = __builtin_amdgcn_mfma_f32_16x16x32_bf16(a, wl, ac1, 0, 0, 0);
    a = na; wh = nh2; wl = nl2;
  }
  ac0 = __builtin_amdgcn_mfma_f32_16x16x32_bf16(a, wh, ac0, 0, 0, 0);
  ac1 = __builtin_amdgcn_mfma_f32_16x16x32_bf16(a, wl, ac1, 0, 0, 0);
  float* dst = part + (kq * 2 + nt2) * 256;
  #pragma unroll
  for (int r = 0; r < 4; ++r)
    dst[(quad * 4 + r) * 16 + ln15] = ac0[r] + ac1[r];
  __syncthreads();

  if (t < 512) {
    const int im = t >> 5, ch = t & 31;
    const int ntc = ch >> 4, c15 = ch & 15;
    float v = bd1g[nh * 32 + ch];
    #pragma unroll
    for (int k8 = 0; k8 < 8; ++k8)
      v += part[(k8 * 2 + ntc) * 256 + im * 16 + c15];
    hvg[(long)(g * 16 + im) * 64 + nh * 32 + ch] = fmaxf(v, 0.f);
  }
}

// ---- dense2 + softmax: 512 blocks x 256 thr, 4 images each
__global__ __launch_bounds__(256) void dense_fin(
    const float* __restrict__ hvg, const float* __restrict__ wd2g,
    const float* __restrict__ bd2g, float* __restrict__ out)
{
  __shared__ float shv[4][64];
  __shared__ float lg[4][12];
  __shared__ float le[4][12];
  const int t = threadIdx.x;
  const int il = t >> 6, ch = t & 63;
  const long img = (long)blockIdx.x * 4 + il;
  shv[il][ch] = hvg[img * 64 + ch];
  __syncthreads();
  if (ch < 10) {
    float a2 = bd2g[ch];
    #pragma unroll
    for (int k = 0; k < 64; ++k) a2 = fmaf(shv[il][k], wd2g[k * 10 + ch], a2);
    lg[il][ch] = a2;
  }
  __syncthreads();
  if (ch < 10) {
    float m = lg[il][0];
    #pragma unroll
    for (int i = 1; i < 10; ++i) m = fmaxf(m, lg[il][i]);
    le[il][ch] = expf(lg[il][ch] - m);
  }
  __syncthreads();
  if (ch < 10) {
    float s = 0.f;
    #pragma unroll
    for (int i = 0; i < 10; ++i) s += le[il][i];
    out[img * 10 + ch] = le[il][ch] / s;
  }
}

extern "C" void kernel_launch(void* const* d_in, const int* in_sizes, int n_in,
                              void* d_out, int out_size, void* d_ws, size_t ws_size,
                              hipStream_t stream) {
  (void)in_sizes; (void)n_in; (void)out_size; (void)ws_size;
  const float* x   = (const float*)d_in[0];
  const float* w1  = (const float*)d_in[1];
  const float* b1  = (const float*)d_in[2];
  const float* w2  = (const float*)d_in[3];
  const float* b2  = (const float*)d_in[4];
  const float* w3  = (const float*)d_in[5];
  const float* b3  = (const float*)d_in[6];
  const float* wd1 = (const float*)d_in[7];
  const float* bd1 = (const float*)d_in[8];
  const float* wd2 = (const float*)d_in[9];
  const float* bd2 = (const float*)d_in[10];
  float* out = (float*)d_out;
  ushortT* wsu = (ushortT*)d_ws;
  ushortT* s3g = wsu + S3F_OFF;
  float* hvg = (float*)d_ws + HVF_OFF;

  hipLaunchKernelGGL(prep_w, dim3(266), dim3(256), 0, stream, w1, w2, w3, wd1, wsu);
  hipLaunchKernelGGL(conv_fused, dim3(NBATCH), dim3(256), 0, stream,
                     x, b1, b2, b3, wsu, s3g);
  hipLaunchKernelGGL(dense1_half, dim3(256), dim3(1024), 0, stream,
                     wsu, bd1, hvg);
  hipLaunchKernelGGL(dense_fin, dim3(NBATCH / 4), dim3(256), 0, stream,
                     hvg, wd2, bd2, out);
}